// Round 2
// 660.518 us; speedup vs baseline: 1.3237x; 1.3237x over previous
//
#include <hip/hip_runtime.h>
#include <hip/hip_bf16.h>
#include <stdint.h>

// MultiHeadAttention on MI355X (gfx950), bf16 MFMA pipeline.
// Stages:
//   1. conv_x: x fp32 -> bf16
//   2. transpose_w: Wq/Wk/Wv/Wo fp32 [K x N] -> bf16 W^T [N x K] (packed, w=0..3)
//   3. pack_bias: bq|bk|bv -> [2304]
//   4. gemm<QKV>:  [8192x2304x768] -> q (pre-scaled by 0.125), k [B,H,N,D] bf16, vT [B,H,D,N] bf16
//   5. fused_attn: per (b,h, 128 q-rows): flash-style 2-phase
//        phase 1: stream K tiles, QK^T MFMA, online row max/exp-sum (no global traffic)
//        phase 2: re-stream K+V, recompute S, normalize, write fp32 probs ONCE (weights output),
//                 bf16 P -> LDS, PV MFMA accumulate -> o bf16 [8192x768]
//   6. gemm<OUT>: [8192x768x768] + bo -> d_out fp32
// Removes vs unfused: raw-score write (402 MB), softmax read+write (804 MB), PV probs read (402 MB).

#define DIM 768
#define NHEADS 12
#define HDIM 64
#define BATCH 8
#define SEQ 1024
#define TOKENS (BATCH * SEQ) /* 8192 */
#define NQKV (3 * DIM)       /* 2304 */

typedef __bf16 bf16x8 __attribute__((ext_vector_type(8)));
typedef float f32x4 __attribute__((ext_vector_type(4)));

__device__ __forceinline__ unsigned int f2bf(float f) {
  unsigned int x = __float_as_uint(f);
  return (x + 0x7fffu + ((x >> 16) & 1u)) >> 16; // RNE bf16, returned in low 16 bits
}

// ---------------- conversion / packing kernels ----------------

__global__ __launch_bounds__(256) void conv_x_kernel(const float* __restrict__ x,
                                                     unsigned short* __restrict__ xb) {
  int i = blockIdx.x * 256 + threadIdx.x; // one float4 per thread
  float4 v = *((const float4*)x + i);
  uint2 o;
  o.x = f2bf(v.x) | (f2bf(v.y) << 16);
  o.y = f2bf(v.z) | (f2bf(v.w) << 16);
  *((uint2*)xb + i) = o;
}

__global__ __launch_bounds__(256) void transpose_w_kernel(const float* __restrict__ Wq,
                                                          const float* __restrict__ Wk,
                                                          const float* __restrict__ Wv,
                                                          const float* __restrict__ Wo,
                                                          unsigned short* __restrict__ WT) {
  __shared__ float tile[32][33];
  const float* W = (blockIdx.z == 0) ? Wq : (blockIdx.z == 1) ? Wk : (blockIdx.z == 2) ? Wv : Wo;
  int tx = threadIdx.x & 31, ty = threadIdx.x >> 5; // 32 x 8
  int k0 = blockIdx.y * 32, n0 = blockIdx.x * 32;
#pragma unroll
  for (int r = ty; r < 32; r += 8) tile[r][tx] = W[(size_t)(k0 + r) * DIM + n0 + tx];
  __syncthreads();
  unsigned short* dst = WT + (size_t)blockIdx.z * DIM * DIM;
#pragma unroll
  for (int r = ty; r < 32; r += 8)
    dst[(size_t)(n0 + r) * DIM + k0 + tx] = (unsigned short)f2bf(tile[tx][r]);
}

__global__ __launch_bounds__(256) void pack_bias_kernel(const float* __restrict__ bq,
                                                        const float* __restrict__ bk,
                                                        const float* __restrict__ bv,
                                                        float* __restrict__ bqkv) {
  int i = blockIdx.x * 256 + threadIdx.x;
  if (i < NQKV) bqkv[i] = (i < DIM) ? bq[i] : (i < 2 * DIM) ? bk[i - DIM] : bv[i - 2 * DIM];
}

// ---------------- generic batched GEMM-BT (bf16 MFMA) ----------------
// C[M x N] = A[M x K] * B^T  with BT[N x K] bf16 row-major.
// Block: 256 thr = 4 waves (2x2), tile 128x128, BK=32, wave tile 64x64 (4x4 MFMA 16x16x32).
// MODE 0 = QKV scatter (q scaled by 0.125), 3 = out projection (+bias fp32)

template <int MODE, typename TA>
__global__ __launch_bounds__(256) void gemm_bt_kernel(
    const TA* __restrict__ A, const unsigned short* __restrict__ B,
    const float* __restrict__ bias, float* __restrict__ outF,
    unsigned short* __restrict__ outA, unsigned short* __restrict__ outB,
    unsigned short* __restrict__ outC, int M, int N, int K, int lda, int ldb,
    long long strideA, long long strideB, float scale) {
  __shared__ alignas(16) unsigned short As[128 * 40];
  __shared__ alignas(16) unsigned short Bs[128 * 40];

  const int z = blockIdx.z;
  A += (long long)z * strideA;
  B += (long long)z * strideB;

  const int t = threadIdx.x;
  const int lane = t & 63;
  const int w = t >> 6;
  const int wm = w >> 1, wn = w & 1;
  const int quad = lane >> 4, l15 = lane & 15;
  const int bm = blockIdx.y, bn = blockIdx.x;

  const f32x4 zero4 = {0.f, 0.f, 0.f, 0.f};
  f32x4 acc[4][4];
#pragma unroll
  for (int i = 0; i < 4; i++)
#pragma unroll
    for (int j = 0; j < 4; j++) acc[i][j] = zero4;

  for (int bk = 0; bk < K; bk += 32) {
#pragma unroll
    for (int c = 0; c < 2; c++) {
      int chunk = t + c * 256;
      int row = chunk >> 2, seg = chunk & 3;
      long long g = (long long)(bm * 128 + row) * lda + bk + seg * 8;
      uint4 v;
      if constexpr (sizeof(TA) == 2) {
        v = *(const uint4*)((const unsigned short*)A + g);
      } else {
        const float* Af = (const float*)A + g;
        float4 f0 = *(const float4*)Af;
        float4 f1 = *(const float4*)(Af + 4);
        v.x = f2bf(f0.x) | (f2bf(f0.y) << 16);
        v.y = f2bf(f0.z) | (f2bf(f0.w) << 16);
        v.z = f2bf(f1.x) | (f2bf(f1.y) << 16);
        v.w = f2bf(f1.z) | (f2bf(f1.w) << 16);
      }
      *(uint4*)(&As[row * 40 + seg * 8]) = v;
    }
#pragma unroll
    for (int c = 0; c < 2; c++) {
      int chunk = t + c * 256;
      int row = chunk >> 2, seg = chunk & 3;
      int nrow = bn * 128 + row;
      uint4 v = make_uint4(0u, 0u, 0u, 0u);
      if (nrow < N) v = *(const uint4*)(B + (long long)nrow * ldb + bk + seg * 8);
      *(uint4*)(&Bs[row * 40 + seg * 8]) = v;
    }
    __syncthreads();

    bf16x8 a[4], b[4];
#pragma unroll
    for (int i = 0; i < 4; i++)
      a[i] = *(const bf16x8*)(&As[(wm * 64 + i * 16 + l15) * 40 + quad * 8]);
#pragma unroll
    for (int j = 0; j < 4; j++)
      b[j] = *(const bf16x8*)(&Bs[(wn * 64 + j * 16 + l15) * 40 + quad * 8]);
#pragma unroll
    for (int i = 0; i < 4; i++)
#pragma unroll
      for (int j = 0; j < 4; j++)
        acc[i][j] = __builtin_amdgcn_mfma_f32_16x16x32_bf16(a[i], b[j], acc[i][j], 0, 0, 0);
    __syncthreads();
  }

// ---- epilogue: C/D layout col = lane&15, row = quad*4 + reg (m89-verified) ----
#pragma unroll
  for (int i = 0; i < 4; i++) {
#pragma unroll
    for (int j = 0; j < 4; j++) {
#pragma unroll
      for (int r = 0; r < 4; r++) {
        int row = bm * 128 + wm * 64 + i * 16 + quad * 4 + r;
        int col = bn * 128 + wn * 64 + j * 16 + l15;
        float v = acc[i][j][r];
        if constexpr (MODE == 0) { // QKV scatter
          v += bias[col];
          int b_ = row >> 10, nseq = row & 1023;
          int wsel = col / DIM, nn = col - wsel * DIM;
          int h = nn >> 6, d = nn & 63;
          long long bh = (long long)b_ * NHEADS + h;
          if (wsel == 0) // q pre-scaled by 1/sqrt(HDIM); exact pow2 scale before RNE
            outA[(bh * SEQ + nseq) * HDIM + d] = (unsigned short)f2bf(v * 0.125f);
          else if (wsel == 1)
            outB[(bh * SEQ + nseq) * HDIM + d] = (unsigned short)f2bf(v); // k [B,H,N,D]
          else
            outC[(bh * HDIM + d) * SEQ + nseq] = (unsigned short)f2bf(v); // vT [B,H,D,N]
        } else { // out projection fp32 + bias
          outF[(long long)row * DIM + col] = v + bias[col];
        }
      }
    }
  }
  (void)scale;
  (void)outF;
}

// ---------------- fused attention: scores + softmax + PV ----------------
// Grid: (mblk 0..7, z 0..95). Block 256 thr = 4 waves; wave w owns q-rows w*32..w*32+31.
// Phase 1: 8 K-tiles, QK^T (Q frags in regs, pre-scaled), online row max m / exp-sum s.
// Phase 2: 8 K+V tiles, recompute S, p = exp(S-m)/s, write fp32 probs (weights output),
//          bf16 p -> Ps (per-wave row slice, no cross-wave barrier needed), PV MFMA.

__global__ __launch_bounds__(256, 2) void fused_attn_kernel(
    const unsigned short* __restrict__ qm, const unsigned short* __restrict__ km,
    const unsigned short* __restrict__ vm, float* __restrict__ probs,
    unsigned short* __restrict__ om) {
  // strides padded to stay 16B-aligned and spread b128 reads across bank groups
  __shared__ alignas(16) unsigned short Ks[128][72];  // K tile [j 0..127][d 0..63]
  __shared__ alignas(16) unsigned short Vs[64][136];  // V^T tile [d 0..63][j 0..127]
  __shared__ alignas(16) unsigned short Ps[128][136]; // P tile [qrow 0..127][j 0..127]

  const int z = blockIdx.y, mblk = blockIdx.x;
  const int bb = z / NHEADS, hh = z - bb * NHEADS;
  const unsigned short* qb = qm + (size_t)z * SEQ * HDIM;
  const unsigned short* kb = km + (size_t)z * SEQ * HDIM;
  const unsigned short* vb = vm + (size_t)z * HDIM * SEQ;
  float* pz = probs + (size_t)z * SEQ * SEQ;

  const int t = threadIdx.x;
  const int w = t >> 6;
  const int quad = (t & 63) >> 4, l15 = t & 15;
  const int rw = w * 32; // wave's row base within the 128-row block

  // Q fragments in registers (already scaled by 0.125 in QKV epilogue)
  bf16x8 aq[2][2];
#pragma unroll
  for (int i = 0; i < 2; i++)
#pragma unroll
    for (int kk = 0; kk < 2; kk++)
      aq[i][kk] = *(const bf16x8*)(qb + (size_t)(mblk * 128 + rw + i * 16 + l15) * HDIM +
                                   kk * 32 + quad * 8);

  float m[2][4], s[2][4]; // per-lane row stats: row = rw + i*16 + quad*4 + r
#pragma unroll
  for (int i = 0; i < 2; i++)
#pragma unroll
    for (int r = 0; r < 4; r++) {
      m[i][r] = -1e30f;
      s[i][r] = 0.f;
    }

  const f32x4 zero4 = {0.f, 0.f, 0.f, 0.f};

  // ---- phase 1: online row max & exp-sum across all 8 j-tiles ----
  for (int jt = 0; jt < 8; jt++) {
#pragma unroll
    for (int c = 0; c < 4; c++) {
      int chunk = t + c * 256;
      int row = chunk >> 3, seg = chunk & 7;
      *(uint4*)(&Ks[row][seg * 8]) =
          *(const uint4*)(kb + (size_t)(jt * 128 + row) * HDIM + seg * 8);
    }
    __syncthreads();
    f32x4 acc[2][8];
#pragma unroll
    for (int i = 0; i < 2; i++)
#pragma unroll
      for (int j = 0; j < 8; j++) acc[i][j] = zero4;
#pragma unroll
    for (int j = 0; j < 8; j++) {
      bf16x8 b0 = *(const bf16x8*)(&Ks[j * 16 + l15][quad * 8]);
      bf16x8 b1 = *(const bf16x8*)(&Ks[j * 16 + l15][32 + quad * 8]);
#pragma unroll
      for (int i = 0; i < 2; i++) {
        acc[i][j] = __builtin_amdgcn_mfma_f32_16x16x32_bf16(aq[i][0], b0, acc[i][j], 0, 0, 0);
        acc[i][j] = __builtin_amdgcn_mfma_f32_16x16x32_bf16(aq[i][1], b1, acc[i][j], 0, 0, 0);
      }
    }
    // row stats: reduce over 8 j-frags in regs, then over 16 col-lanes (same quad = same rows)
#pragma unroll
    for (int i = 0; i < 2; i++)
#pragma unroll
      for (int r = 0; r < 4; r++) {
        float tm = acc[i][0][r];
#pragma unroll
        for (int j = 1; j < 8; j++) tm = fmaxf(tm, acc[i][j][r]);
#pragma unroll
        for (int mk = 1; mk < 16; mk <<= 1) tm = fmaxf(tm, __shfl_xor(tm, mk, 64));
        float mn = fmaxf(m[i][r], tm);
        float se = 0.f;
#pragma unroll
        for (int j = 0; j < 8; j++) se += __expf(acc[i][j][r] - mn);
#pragma unroll
        for (int mk = 1; mk < 16; mk <<= 1) se += __shfl_xor(se, mk, 64);
        s[i][r] = s[i][r] * __expf(m[i][r] - mn) + se;
        m[i][r] = mn;
      }
    __syncthreads();
  }

  float is_[2][4];
#pragma unroll
  for (int i = 0; i < 2; i++)
#pragma unroll
    for (int r = 0; r < 4; r++) is_[i][r] = 1.0f / s[i][r];

  f32x4 oacc[2][4];
#pragma unroll
  for (int i = 0; i < 2; i++)
#pragma unroll
    for (int dj = 0; dj < 4; dj++) oacc[i][dj] = zero4;

  // ---- phase 2: recompute, normalize, write probs once, PV accumulate ----
  for (int jt = 0; jt < 8; jt++) {
#pragma unroll
    for (int c = 0; c < 4; c++) {
      int chunk = t + c * 256;
      int row = chunk >> 3, seg = chunk & 7;
      *(uint4*)(&Ks[row][seg * 8]) =
          *(const uint4*)(kb + (size_t)(jt * 128 + row) * HDIM + seg * 8);
    }
#pragma unroll
    for (int c = 0; c < 4; c++) {
      int chunk = t + c * 256;
      int row = chunk >> 4, seg = chunk & 15;
      *(uint4*)(&Vs[row][seg * 8]) =
          *(const uint4*)(vb + (size_t)row * SEQ + jt * 128 + seg * 8);
    }
    __syncthreads();
    f32x4 acc[2][8];
#pragma unroll
    for (int i = 0; i < 2; i++)
#pragma unroll
      for (int j = 0; j < 8; j++) acc[i][j] = zero4;
#pragma unroll
    for (int j = 0; j < 8; j++) {
      bf16x8 b0 = *(const bf16x8*)(&Ks[j * 16 + l15][quad * 8]);
      bf16x8 b1 = *(const bf16x8*)(&Ks[j * 16 + l15][32 + quad * 8]);
#pragma unroll
      for (int i = 0; i < 2; i++) {
        acc[i][j] = __builtin_amdgcn_mfma_f32_16x16x32_bf16(aq[i][0], b0, acc[i][j], 0, 0, 0);
        acc[i][j] = __builtin_amdgcn_mfma_f32_16x16x32_bf16(aq[i][1], b1, acc[i][j], 0, 0, 0);
      }
    }
    // normalize, write fp32 probs (the mandatory weights output), stage bf16 P
#pragma unroll
    for (int i = 0; i < 2; i++)
#pragma unroll
      for (int j = 0; j < 8; j++) {
        int colg = jt * 128 + j * 16 + l15;
#pragma unroll
        for (int r = 0; r < 4; r++) {
          float p = __expf(acc[i][j][r] - m[i][r]) * is_[i][r];
          int rloc = rw + i * 16 + quad * 4 + r;
          pz[(size_t)(mblk * 128 + rloc) * SEQ + colg] = p;
          Ps[rloc][j * 16 + l15] = (unsigned short)f2bf(p);
        }
      }
    // PV: each wave reads only its own Ps row slice -> intra-wave lgkmcnt ordering suffices
#pragma unroll
    for (int kk = 0; kk < 4; kk++) {
      bf16x8 ap0 = *(const bf16x8*)(&Ps[rw + l15][kk * 32 + quad * 8]);
      bf16x8 ap1 = *(const bf16x8*)(&Ps[rw + 16 + l15][kk * 32 + quad * 8]);
#pragma unroll
      for (int dj = 0; dj < 4; dj++) {
        bf16x8 bv = *(const bf16x8*)(&Vs[dj * 16 + l15][kk * 32 + quad * 8]);
        oacc[0][dj] = __builtin_amdgcn_mfma_f32_16x16x32_bf16(ap0, bv, oacc[0][dj], 0, 0, 0);
        oacc[1][dj] = __builtin_amdgcn_mfma_f32_16x16x32_bf16(ap1, bv, oacc[1][dj], 0, 0, 0);
      }
    }
    __syncthreads();
  }

  // o write: merged [token][h*64+d] bf16
#pragma unroll
  for (int i = 0; i < 2; i++)
#pragma unroll
    for (int dj = 0; dj < 4; dj++)
#pragma unroll
      for (int r = 0; r < 4; r++) {
        int orow = mblk * 128 + rw + i * 16 + quad * 4 + r;
        om[((size_t)(bb * SEQ + orow)) * DIM + hh * HDIM + dj * 16 + l15] =
            (unsigned short)f2bf(oacc[i][dj][r]);
      }
}

// ---------------- launch ----------------

extern "C" void kernel_launch(void* const* d_in, const int* in_sizes, int n_in,
                              void* d_out, int out_size, void* d_ws, size_t ws_size,
                              hipStream_t stream) {
  const float* x = (const float*)d_in[0];
  const float* Wq = (const float*)d_in[1];
  const float* bq = (const float*)d_in[2];
  const float* Wk = (const float*)d_in[3];
  const float* bk = (const float*)d_in[4];
  const float* Wv = (const float*)d_in[5];
  const float* bv = (const float*)d_in[6];
  const float* Wo = (const float*)d_in[7];
  const float* bo = (const float*)d_in[8];

  char* ws = (char*)d_ws;
  size_t off = 0;
  auto alloc = [&](size_t bytes) {
    void* p = ws + off;
    off = (off + bytes + 255) & ~(size_t)255;
    return p;
  };
  unsigned short* xb = (unsigned short*)alloc((size_t)TOKENS * DIM * 2);
  unsigned short* WT = (unsigned short*)alloc((size_t)4 * DIM * DIM * 2);
  float* bqkv = (float*)alloc((size_t)NQKV * 4);
  unsigned short* q = (unsigned short*)alloc((size_t)TOKENS * DIM * 2);
  unsigned short* kmat = (unsigned short*)alloc((size_t)TOKENS * DIM * 2);
  unsigned short* vT = (unsigned short*)alloc((size_t)TOKENS * DIM * 2);
  unsigned short* o = (unsigned short*)alloc((size_t)TOKENS * DIM * 2);
  (void)ws_size; // needs ~68 MB

  float* outp = (float*)d_out;
  float* probs = outp + (size_t)TOKENS * DIM; // [B,H,N,N] fp32, 402 MB

  conv_x_kernel<<<(TOKENS * DIM / 4) / 256, 256, 0, stream>>>(x, xb);
  transpose_w_kernel<<<dim3(24, 24, 4), 256, 0, stream>>>(Wq, Wk, Wv, Wo, WT);
  pack_bias_kernel<<<9, 256, 0, stream>>>(bq, bk, bv, bqkv);

  // QKV: M=8192, N=2304, K=768 (q written pre-scaled by 0.125)
  gemm_bt_kernel<0, unsigned short><<<dim3(18, 64, 1), 256, 0, stream>>>(
      xb, WT, bqkv, nullptr, q, kmat, vT, TOKENS, NQKV, DIM, DIM, DIM, 0, 0, 0.f);

  // fused scores + softmax + PV: one dispatch, probs written exactly once
  fused_attn_kernel<<<dim3(8, 96), 256, 0, stream>>>(q, kmat, vT, probs, o);

  // out projection: M=8192, N=768, K=768, + bo
  gemm_bt_kernel<3, unsigned short><<<dim3(6, 64, 1), 256, 0, stream>>>(
      o, WT + (size_t)3 * DIM * DIM, bo, outp, nullptr, nullptr, nullptr, TOKENS, DIM, DIM,
      DIM, DIM, 0, 0, 0.f);
}

// Round 3
// 624.571 us; speedup vs baseline: 1.3999x; 1.0576x over previous
//
#include <hip/hip_runtime.h>
#include <hip/hip_bf16.h>
#include <stdint.h>

// MultiHeadAttention on MI355X (gfx950), bf16 MFMA pipeline.
//   1. conv_x: x fp32 -> bf16
//   2. transpose_w: Wq/Wk/Wv/Wo fp32 [K x N] -> bf16 W^T [N x K] (packed, w=0..3)
//   3. pack_bias: bq|bk|bv -> [2304]
//   4. gemm<0>: [8192x2304x768] -> q (pre-scaled 0.125), k, v all [B,H,N,D] bf16 (coalesced)
//   5. transpose_v: v [B,H,N,D] -> vT [B,H,D,N]
//   6. fused_attn: flash-style 2-phase; probs written once (nontemporal), PV in-block
//   7. gemm<1>: [8192x768x768] + bo -> d_out fp32
// GEMM + attn staging via global_load_lds w=16 (m97 pattern), seg-XOR swizzle both-sides.

#define DIM 768
#define NHEADS 12
#define HDIM 64
#define BATCH 8
#define SEQ 1024
#define TOKENS (BATCH * SEQ) /* 8192 */
#define NQKV (3 * DIM)       /* 2304 */

typedef __bf16 bf16x8 __attribute__((ext_vector_type(8)));
typedef float f32x4 __attribute__((ext_vector_type(4)));

__device__ __forceinline__ unsigned int f2bf(float f) {
  unsigned int x = __float_as_uint(f);
  return (x + 0x7fffu + ((x >> 16) & 1u)) >> 16; // RNE bf16, low 16 bits
}

// async global->LDS, 16B per lane; LDS dest is wave-uniform base + lane*16
__device__ __forceinline__ void gload16(const void* g, void* l) {
  __builtin_amdgcn_global_load_lds(
      (const __attribute__((address_space(1))) void*)g,
      (__attribute__((address_space(3))) void*)l, 16, 0, 0);
}

// ---------------- conversion / packing kernels ----------------

__global__ __launch_bounds__(256) void conv_x_kernel(const float* __restrict__ x,
                                                     unsigned short* __restrict__ xb) {
  int i = blockIdx.x * 256 + threadIdx.x; // one float4 per thread
  float4 v = *((const float4*)x + i);
  uint2 o;
  o.x = f2bf(v.x) | (f2bf(v.y) << 16);
  o.y = f2bf(v.z) | (f2bf(v.w) << 16);
  *((uint2*)xb + i) = o;
}

__global__ __launch_bounds__(256) void transpose_w_kernel(const float* __restrict__ Wq,
                                                          const float* __restrict__ Wk,
                                                          const float* __restrict__ Wv,
                                                          const float* __restrict__ Wo,
                                                          unsigned short* __restrict__ WT) {
  __shared__ float tile[32][33];
  const float* W = (blockIdx.z == 0) ? Wq : (blockIdx.z == 1) ? Wk : (blockIdx.z == 2) ? Wv : Wo;
  int tx = threadIdx.x & 31, ty = threadIdx.x >> 5; // 32 x 8
  int k0 = blockIdx.y * 32, n0 = blockIdx.x * 32;
#pragma unroll
  for (int r = ty; r < 32; r += 8) tile[r][tx] = W[(size_t)(k0 + r) * DIM + n0 + tx];
  __syncthreads();
  unsigned short* dst = WT + (size_t)blockIdx.z * DIM * DIM;
#pragma unroll
  for (int r = ty; r < 32; r += 8)
    dst[(size_t)(n0 + r) * DIM + k0 + tx] = (unsigned short)f2bf(tile[tx][r]);
}

__global__ __launch_bounds__(256) void pack_bias_kernel(const float* __restrict__ bq,
                                                        const float* __restrict__ bk,
                                                        const float* __restrict__ bv,
                                                        float* __restrict__ bqkv) {
  int i = blockIdx.x * 256 + threadIdx.x;
  if (i < NQKV) bqkv[i] = (i < DIM) ? bq[i] : (i < 2 * DIM) ? bk[i - DIM] : bv[i - 2 * DIM];
}

// v [B,H,N,D] -> vT [B,H,D,N], 64x64 bf16 tiles. Grid (16, 96).
__global__ __launch_bounds__(256) void transpose_v_kernel(const unsigned short* __restrict__ v,
                                                          unsigned short* __restrict__ vT) {
  __shared__ unsigned short td[64][66]; // pad 66: rows 16 apart land on different banks
  const int z = blockIdx.y;
  const int n0 = blockIdx.x * 64;
  const unsigned short* vb = v + (size_t)z * SEQ * HDIM;
  unsigned short* ob = vT + (size_t)z * HDIM * SEQ;
  const int t = threadIdx.x;
  const int rr = t >> 2, cc = (t & 3) * 16;
  *(uint4*)&td[rr][cc] = *(const uint4*)(vb + (size_t)(n0 + rr) * HDIM + cc);
  *(uint4*)&td[rr][cc + 8] = *(const uint4*)(vb + (size_t)(n0 + rr) * HDIM + cc + 8);
  __syncthreads();
  const int d = t >> 2, ns = (t & 3) * 16;
  union { uint4 q[2]; unsigned short u[16]; } tmp;
#pragma unroll
  for (int e = 0; e < 16; e++) tmp.u[e] = td[ns + e][d];
  *(uint4*)(ob + (size_t)d * SEQ + n0 + ns) = tmp.q[0];
  *(uint4*)(ob + (size_t)d * SEQ + n0 + ns + 8) = tmp.q[1];
}

// ---------------- GEMM-BT (bf16 MFMA, global_load_lds staging) ----------------
// C[M x N] = A[M x K] * B^T, BT[N x K] bf16 row-major. Tile 128x128, BK=32, 4 waves.
// Requires M%128==0, N%128==0 (grid-implied), K%32==0.
// LDS [128][32] linear (needed by global_load_lds), seg-XOR swizzle seg^=(row>>1)&3
// applied on BOTH global source and LDS read -> 2-way (free) bank aliasing.
// MODE 0 = QKV scatter (q scaled 0.125, all outputs [B,H,N,D]), 1 = out proj (+bias fp32)

template <int MODE>
__global__ __launch_bounds__(256) void gemm_bt_kernel(
    const unsigned short* __restrict__ A, const unsigned short* __restrict__ B,
    const float* __restrict__ bias, float* __restrict__ outF,
    unsigned short* __restrict__ outQ, unsigned short* __restrict__ outK,
    unsigned short* __restrict__ outV, int K, int lda, int ldb) {
  __shared__ alignas(16) unsigned short As[128 * 32];
  __shared__ alignas(16) unsigned short Bs[128 * 32];

  const int t = threadIdx.x;
  const int lane = t & 63;
  const int w = t >> 6;
  const int wm = w >> 1, wn = w & 1;
  const int quad = lane >> 4, l15 = lane & 15;
  const int bm = blockIdx.y, bn = blockIdx.x;

  const int srow = lane >> 2; // 0..15 within a 1KB staging chunk
  const int segl = lane & 3;  // LDS 16B-seg within 64B row

  const unsigned short* Abase = A + (size_t)(bm * 128) * lda;
  const unsigned short* Bbase = B + (size_t)(bn * 128) * ldb;

  const f32x4 zero4 = {0.f, 0.f, 0.f, 0.f};
  f32x4 acc[4][4];
#pragma unroll
  for (int i = 0; i < 4; i++)
#pragma unroll
    for (int j = 0; j < 4; j++) acc[i][j] = zero4;

  for (int bk = 0; bk < K; bk += 32) {
#pragma unroll
    for (int c = 0; c < 2; c++) {
      int g = w * 2 + c;          // chunk 0..7 (16 rows x 64B each)
      int row = g * 16 + srow;
      int segg = segl ^ ((row >> 1) & 3); // pre-swizzled global source
      gload16(Abase + (size_t)row * lda + bk + segg * 8, &As[g * 512]);
      gload16(Bbase + (size_t)row * ldb + bk + segg * 8, &Bs[g * 512]);
    }
    __syncthreads(); // compiler drains vmcnt(0) here -> staging complete

    bf16x8 a[4], b[4];
#pragma unroll
    for (int i = 0; i < 4; i++) {
      int r = wm * 64 + i * 16 + l15;
      a[i] = *(const bf16x8*)(&As[r * 32 + ((quad ^ ((r >> 1) & 3)) * 8)]);
    }
#pragma unroll
    for (int j = 0; j < 4; j++) {
      int r = wn * 64 + j * 16 + l15;
      b[j] = *(const bf16x8*)(&Bs[r * 32 + ((quad ^ ((r >> 1) & 3)) * 8)]);
    }
#pragma unroll
    for (int i = 0; i < 4; i++)
#pragma unroll
      for (int j = 0; j < 4; j++)
        acc[i][j] = __builtin_amdgcn_mfma_f32_16x16x32_bf16(a[i], b[j], acc[i][j], 0, 0, 0);
    __syncthreads();
  }

// ---- epilogue: C/D layout col = lane&15, row = quad*4 + reg (m89-verified) ----
#pragma unroll
  for (int i = 0; i < 4; i++) {
#pragma unroll
    for (int j = 0; j < 4; j++) {
#pragma unroll
      for (int r = 0; r < 4; r++) {
        int row = bm * 128 + wm * 64 + i * 16 + quad * 4 + r;
        int col = bn * 128 + wn * 64 + j * 16 + l15;
        float v = acc[i][j][r] + bias[col];
        if constexpr (MODE == 0) { // QKV scatter, all [B,H,N,D] (16-lane contiguous d)
          int b_ = row >> 10, nseq = row & 1023;
          int wsel = col / DIM, nn = col - wsel * DIM;
          int h = nn >> 6, d = nn & 63;
          size_t idx = ((size_t)(b_ * NHEADS + h) * SEQ + nseq) * HDIM + d;
          if (wsel == 0)
            outQ[idx] = (unsigned short)f2bf(v * 0.125f); // q pre-scaled 1/sqrt(HDIM)
          else if (wsel == 1)
            outK[idx] = (unsigned short)f2bf(v);
          else
            outV[idx] = (unsigned short)f2bf(v);
        } else { // out projection fp32 + bias
          outF[(size_t)row * DIM + col] = v;
        }
      }
    }
  }
}

// ---------------- fused attention: scores + softmax + PV ----------------
// Grid: (mblk 0..7, z 0..95). 256 thr = 4 waves; wave w owns q-rows w*32..w*32+31.
// Phase 1: 8 K-tiles, QK^T (Q frags in regs, pre-scaled), online row max/exp-sum.
// Phase 2: 8 K+V tiles, recompute S, p = exp(S-m)/s, nontemporal fp32 probs write,
//          bf16 p -> Ps (per-wave rows), PV MFMA accumulate.
// K/V staged via global_load_lds into linear LDS with XOR swizzles:
//   Ks rows 128B (8 segs): seg ^= row&7 ; Vs rows 256B (16 segs): seg ^= row&15.

__global__ __launch_bounds__(256, 2) void fused_attn_kernel(
    const unsigned short* __restrict__ qm, const unsigned short* __restrict__ km,
    const unsigned short* __restrict__ vm, float* __restrict__ probs,
    unsigned short* __restrict__ om) {
  __shared__ alignas(16) unsigned short Ks[128 * 64];  // K tile [j][d], swizzled
  __shared__ alignas(16) unsigned short Vs[64 * 128];  // V^T tile [d][j], swizzled
  __shared__ alignas(16) unsigned short Ps[128][136];  // P tile [qrow][j]

  const int z = blockIdx.y, mblk = blockIdx.x;
  const int bb = z / NHEADS, hh = z - bb * NHEADS;
  const unsigned short* qb = qm + (size_t)z * SEQ * HDIM;
  const unsigned short* kb = km + (size_t)z * SEQ * HDIM;
  const unsigned short* vb = vm + (size_t)z * HDIM * SEQ;
  float* pz = probs + (size_t)z * SEQ * SEQ;

  const int t = threadIdx.x;
  const int lane = t & 63;
  const int w = t >> 6;
  const int quad = lane >> 4, l15 = lane & 15;
  const int rw = w * 32; // wave's row base within the 128-row block

  // Q fragments in registers (already scaled by 0.125 in QKV epilogue)
  bf16x8 aq[2][2];
#pragma unroll
  for (int i = 0; i < 2; i++)
#pragma unroll
    for (int kk = 0; kk < 2; kk++)
      aq[i][kk] = *(const bf16x8*)(qb + (size_t)(mblk * 128 + rw + i * 16 + l15) * HDIM +
                                   kk * 32 + quad * 8);

  float m[2][4], s[2][4]; // per-lane row stats: row = rw + i*16 + quad*4 + r
#pragma unroll
  for (int i = 0; i < 2; i++)
#pragma unroll
    for (int r = 0; r < 4; r++) {
      m[i][r] = -1e30f;
      s[i][r] = 0.f;
    }

  const f32x4 zero4 = {0.f, 0.f, 0.f, 0.f};

  // ---- phase 1: online row max & exp-sum across all 8 j-tiles ----
  for (int jt = 0; jt < 8; jt++) {
#pragma unroll
    for (int c = 0; c < 4; c++) {
      int g = w * 4 + c;              // chunk 0..15 (8 rows x 128B)
      int row = g * 8 + (lane >> 3);
      int segg = (lane & 7) ^ (row & 7);
      gload16(kb + (size_t)(jt * 128 + row) * HDIM + segg * 8, &Ks[g * 512]);
    }
    __syncthreads();
    f32x4 acc[2][8];
#pragma unroll
    for (int i = 0; i < 2; i++)
#pragma unroll
      for (int j = 0; j < 8; j++) acc[i][j] = zero4;
#pragma unroll
    for (int j = 0; j < 8; j++) {
      int kr = j * 16 + l15;
      bf16x8 b0 = *(const bf16x8*)(&Ks[kr * 64 + ((quad ^ (kr & 7)) * 8)]);
      bf16x8 b1 = *(const bf16x8*)(&Ks[kr * 64 + (((4 + quad) ^ (kr & 7)) * 8)]);
#pragma unroll
      for (int i = 0; i < 2; i++) {
        acc[i][j] = __builtin_amdgcn_mfma_f32_16x16x32_bf16(aq[i][0], b0, acc[i][j], 0, 0, 0);
        acc[i][j] = __builtin_amdgcn_mfma_f32_16x16x32_bf16(aq[i][1], b1, acc[i][j], 0, 0, 0);
      }
    }
    // row stats: reduce over 8 j-frags in regs, then over 16 col-lanes (same quad = same rows)
#pragma unroll
    for (int i = 0; i < 2; i++)
#pragma unroll
      for (int r = 0; r < 4; r++) {
        float tm = acc[i][0][r];
#pragma unroll
        for (int j = 1; j < 8; j++) tm = fmaxf(tm, acc[i][j][r]);
#pragma unroll
        for (int mk = 1; mk < 16; mk <<= 1) tm = fmaxf(tm, __shfl_xor(tm, mk, 64));
        float mn = fmaxf(m[i][r], tm);
        float se = 0.f;
#pragma unroll
        for (int j = 0; j < 8; j++) se += __expf(acc[i][j][r] - mn);
#pragma unroll
        for (int mk = 1; mk < 16; mk <<= 1) se += __shfl_xor(se, mk, 64);
        s[i][r] = s[i][r] * __expf(m[i][r] - mn) + se;
        m[i][r] = mn;
      }
    __syncthreads();
  }

  float is_[2][4];
#pragma unroll
  for (int i = 0; i < 2; i++)
#pragma unroll
    for (int r = 0; r < 4; r++) is_[i][r] = 1.0f / s[i][r];

  f32x4 oacc[2][4];
#pragma unroll
  for (int i = 0; i < 2; i++)
#pragma unroll
    for (int dj = 0; dj < 4; dj++) oacc[i][dj] = zero4;

  // ---- phase 2: recompute, normalize, write probs once (nt), PV accumulate ----
  for (int jt = 0; jt < 8; jt++) {
#pragma unroll
    for (int c = 0; c < 4; c++) {
      int g = w * 4 + c;
      int row = g * 8 + (lane >> 3);
      int segg = (lane & 7) ^ (row & 7);
      gload16(kb + (size_t)(jt * 128 + row) * HDIM + segg * 8, &Ks[g * 512]);
    }
#pragma unroll
    for (int c = 0; c < 4; c++) {
      int g = w * 4 + c;              // chunk 0..15 (4 rows x 256B)
      int row = g * 4 + (lane >> 4);  // d 0..63
      int segg = (lane & 15) ^ (row & 15);
      gload16(vb + (size_t)row * SEQ + jt * 128 + segg * 8, &Vs[g * 512]);
    }
    __syncthreads();
    f32x4 acc[2][8];
#pragma unroll
    for (int i = 0; i < 2; i++)
#pragma unroll
      for (int j = 0; j < 8; j++) acc[i][j] = zero4;
#pragma unroll
    for (int j = 0; j < 8; j++) {
      int kr = j * 16 + l15;
      bf16x8 b0 = *(const bf16x8*)(&Ks[kr * 64 + ((quad ^ (kr & 7)) * 8)]);
      bf16x8 b1 = *(const bf16x8*)(&Ks[kr * 64 + (((4 + quad) ^ (kr & 7)) * 8)]);
#pragma unroll
      for (int i = 0; i < 2; i++) {
        acc[i][j] = __builtin_amdgcn_mfma_f32_16x16x32_bf16(aq[i][0], b0, acc[i][j], 0, 0, 0);
        acc[i][j] = __builtin_amdgcn_mfma_f32_16x16x32_bf16(aq[i][1], b1, acc[i][j], 0, 0, 0);
      }
    }
    // normalize, write fp32 probs (mandatory weights output), stage bf16 P
#pragma unroll
    for (int i = 0; i < 2; i++)
#pragma unroll
      for (int j = 0; j < 8; j++) {
        int colg = jt * 128 + j * 16 + l15;
#pragma unroll
        for (int r = 0; r < 4; r++) {
          float p = __expf(acc[i][j][r] - m[i][r]) * is_[i][r];
          int rloc = rw + i * 16 + quad * 4 + r;
          __builtin_nontemporal_store(p, &pz[(size_t)(mblk * 128 + rloc) * SEQ + colg]);
          Ps[rloc][j * 16 + l15] = (unsigned short)f2bf(p);
        }
      }
    // PV: each wave reads only its own Ps row slice -> intra-wave lgkmcnt ordering suffices
#pragma unroll
    for (int kk = 0; kk < 4; kk++) {
      bf16x8 ap0 = *(const bf16x8*)(&Ps[rw + l15][kk * 32 + quad * 8]);
      bf16x8 ap1 = *(const bf16x8*)(&Ps[rw + 16 + l15][kk * 32 + quad * 8]);
#pragma unroll
      for (int dj = 0; dj < 4; dj++) {
        int vr = dj * 16 + l15;
        bf16x8 bv = *(const bf16x8*)(&Vs[vr * 128 + (((kk * 4 + quad) ^ (vr & 15)) * 8)]);
        oacc[0][dj] = __builtin_amdgcn_mfma_f32_16x16x32_bf16(ap0, bv, oacc[0][dj], 0, 0, 0);
        oacc[1][dj] = __builtin_amdgcn_mfma_f32_16x16x32_bf16(ap1, bv, oacc[1][dj], 0, 0, 0);
      }
    }
    __syncthreads();
  }

  // o write: merged [token][h*64+d] bf16
#pragma unroll
  for (int i = 0; i < 2; i++)
#pragma unroll
    for (int dj = 0; dj < 4; dj++)
#pragma unroll
      for (int r = 0; r < 4; r++) {
        int orow = mblk * 128 + rw + i * 16 + quad * 4 + r;
        om[((size_t)(bb * SEQ + orow)) * DIM + hh * HDIM + dj * 16 + l15] =
            (unsigned short)f2bf(oacc[i][dj][r]);
      }
}

// ---------------- launch ----------------

extern "C" void kernel_launch(void* const* d_in, const int* in_sizes, int n_in,
                              void* d_out, int out_size, void* d_ws, size_t ws_size,
                              hipStream_t stream) {
  const float* x = (const float*)d_in[0];
  const float* Wq = (const float*)d_in[1];
  const float* bq = (const float*)d_in[2];
  const float* Wk = (const float*)d_in[3];
  const float* bk = (const float*)d_in[4];
  const float* Wv = (const float*)d_in[5];
  const float* bv = (const float*)d_in[6];
  const float* Wo = (const float*)d_in[7];
  const float* bo = (const float*)d_in[8];

  char* ws = (char*)d_ws;
  size_t off = 0;
  auto alloc = [&](size_t bytes) {
    void* p = ws + off;
    off = (off + bytes + 255) & ~(size_t)255;
    return p;
  };
  unsigned short* xb = (unsigned short*)alloc((size_t)TOKENS * DIM * 2);
  unsigned short* WT = (unsigned short*)alloc((size_t)4 * DIM * DIM * 2);
  float* bqkv = (float*)alloc((size_t)NQKV * 4);
  unsigned short* q = (unsigned short*)alloc((size_t)TOKENS * DIM * 2);
  unsigned short* kmat = (unsigned short*)alloc((size_t)TOKENS * DIM * 2);
  unsigned short* vT = (unsigned short*)alloc((size_t)TOKENS * DIM * 2);
  unsigned short* o = (unsigned short*)alloc((size_t)TOKENS * DIM * 2);
  (void)ws_size; // ~68 MB total (o doubles as v scratch before attn overwrites it)

  float* outp = (float*)d_out;
  float* probs = outp + (size_t)TOKENS * DIM; // [B,H,N,N] fp32, 402 MB

  conv_x_kernel<<<(TOKENS * DIM / 4) / 256, 256, 0, stream>>>(x, xb);
  transpose_w_kernel<<<dim3(24, 24, 4), 256, 0, stream>>>(Wq, Wk, Wv, Wo, WT);
  pack_bias_kernel<<<9, 256, 0, stream>>>(bq, bk, bv, bqkv);

  // QKV: M=8192, N=2304, K=768; v lands in o-buffer as [B,H,N,D] scratch
  gemm_bt_kernel<0><<<dim3(18, 64), 256, 0, stream>>>(xb, WT, bqkv, nullptr, q, kmat, o,
                                                      DIM, DIM, DIM);

  // v [B,H,N,D] -> vT [B,H,D,N]
  transpose_v_kernel<<<dim3(16, 96), 256, 0, stream>>>(o, vT);

  // fused scores + softmax + PV (overwrites o with attention output)
  fused_attn_kernel<<<dim3(8, 96), 256, 0, stream>>>(q, kmat, vT, probs, o);

  // out projection: M=8192, N=768, K=768, + bo
  gemm_bt_kernel<1><<<dim3(6, 64), 256, 0, stream>>>(o, WT + (size_t)3 * DIM * DIM, bo, outp,
                                                     nullptr, nullptr, nullptr, DIM, DIM, DIM);
}